// Round 18
// baseline (1590.351 us; speedup 1.0000x reference)
//
#include <hip/hip_runtime.h>
#include <hip/hip_bf16.h>

// Problem constants
#define NB 4
#define SS 2048
#define HH 1024
#define EE 8
#define KK 2
#define DFF 2730
#define DFFP 2752           // padded to multiple of 64
#define NT (NB*SS)          // 8192 tokens
#define NA (NT*KK)          // 16384 assignments
#define YSZ ((size_t)NT*HH) // 8388608

using bf16x8 = __attribute__((ext_vector_type(8))) short;
using f32x4  = __attribute__((ext_vector_type(4))) float;

__device__ __forceinline__ ushort f2bf(float f) {
  unsigned u = __float_as_uint(f);
  unsigned r = (u + 0x7FFFu + ((u >> 16) & 1u)) >> 16;
  return (ushort)r;
}

__device__ __forceinline__ void gload16(const ushort* g, ushort* s) {
  __builtin_amdgcn_global_load_lds((const __attribute__((address_space(1))) void*)g,
                                   (__attribute__((address_space(3))) void*)s, 16, 0, 0);
}

// ---------------- plain fp32 -> bf16 convert (no transpose) ----------------
__global__ __launch_bounds__(256) void cvt_w_kernel(const float4* __restrict__ in4,
                                                    ushort4* __restrict__ o4, int n4) {
  int i = blockIdx.x * 256 + threadIdx.x;
  if (i >= n4) return;
  float4 v = in4[i];
  ushort4 o;
  o.x = f2bf(v.x); o.y = f2bf(v.y); o.z = f2bf(v.z); o.w = f2bf(v.w);
  o4[i] = o;
}

// ------------- transpose + convert: in[e][K][Nn] fp32 -> out[e][Nnpad][Kpad] bf16 -------------
__global__ __launch_bounds__(256) void transpose_cvt_kernel(
    const float* __restrict__ in, ushort* __restrict__ out,
    int K, int Nn, int Kpad, int Nnpad, long in_estride, long out_estride) {
  __shared__ float t[64][65];   // t[k_local][n_local]
  int e = blockIdx.z;
  const float* ine = in + (size_t)e * in_estride;
  ushort* oute = out + (size_t)e * out_estride;
  int nb = blockIdx.x * 64, kb = blockIdx.y * 64;
  int tid = threadIdx.x;
  int rr = tid >> 4, cc = (tid & 15) * 4;
  if (kb + 64 <= K && nb + 64 <= Nn) {
#pragma unroll
    for (int i = 0; i < 4; ++i) {
      int r = rr + i * 16;
      const float* src = ine + (size_t)(kb + r) * Nn + nb + cc;
      float2 a = *(const float2*)src;
      float2 b = *(const float2*)(src + 2);
      t[r][cc] = a.x; t[r][cc + 1] = a.y; t[r][cc + 2] = b.x; t[r][cc + 3] = b.y;
    }
  } else {
#pragma unroll
    for (int i = 0; i < 4; ++i) {
      int r = rr + i * 16;
      int kg = kb + r;
#pragma unroll
      for (int j = 0; j < 4; ++j) {
        int ng = nb + cc + j;
        t[r][cc + j] = (kg < K && ng < Nn) ? ine[(size_t)kg * Nn + ng] : 0.0f;
      }
    }
  }
  __syncthreads();
  int kq = tid & 15;
#pragma unroll
  for (int i = 0; i < 4; ++i) {
    int nl = rr + i * 16, ng = nb + nl;
    ushort4 v;
    v.x = f2bf(t[kq * 4 + 0][nl]);
    v.y = f2bf(t[kq * 4 + 1][nl]);
    v.z = f2bf(t[kq * 4 + 2][nl]);
    v.w = f2bf(t[kq * 4 + 3][nl]);
    *(ushort4*)&oute[(size_t)ng * Kpad + kb + kq * 4] = v;
  }
}

// ---------------- router (+ fused x->bf16 convert): logits, top2, counts ----------------
__global__ __launch_bounds__(256) void router_kernel(
    const float* __restrict__ x, const float* __restrict__ Wr, const float* __restrict__ br,
    float* __restrict__ logits_out, int* __restrict__ counts,
    int* __restrict__ tok_e, float* __restrict__ tok_w, ushort* __restrict__ xb) {
  int wv = threadIdx.x >> 6, l = threadIdx.x & 63;
  int n = blockIdx.x * 4 + wv;
  const float* xr = x + (size_t)n * HH;
  ushort* xbr = xb + (size_t)n * HH;
  float acc[8] = {0, 0, 0, 0, 0, 0, 0, 0};
#pragma unroll 4
  for (int i = 0; i < 16; ++i) {
    int k = l + i * 64;
    float xv = xr[k];
    xbr[k] = f2bf(xv);              // fused convert (x is read here anyway)
    const float4* w4 = (const float4*)(Wr + (size_t)k * 8);
    float4 a = w4[0], b = w4[1];
    acc[0] += xv * a.x; acc[1] += xv * a.y; acc[2] += xv * a.z; acc[3] += xv * a.w;
    acc[4] += xv * b.x; acc[5] += xv * b.y; acc[6] += xv * b.z; acc[7] += xv * b.w;
  }
#pragma unroll
  for (int s = 1; s < 64; s <<= 1)
#pragma unroll
    for (int e2 = 0; e2 < 8; ++e2) acc[e2] += __shfl_xor(acc[e2], s);
#pragma unroll
  for (int e2 = 0; e2 < 8; ++e2) acc[e2] += br[e2];
  if (l < 8) logits_out[(size_t)n * 8 + l] = acc[l];
  if (l == 0) {
    int i0 = 0;
#pragma unroll
    for (int e2 = 1; e2 < 8; ++e2) if (acc[e2] > acc[i0]) i0 = e2;
    int i1 = (i0 == 0) ? 1 : 0;
#pragma unroll
    for (int e2 = 0; e2 < 8; ++e2) if (e2 != i0 && acc[e2] > acc[i1]) i1 = e2;
    float e10 = __expf(acc[i1] - acc[i0]);
    float w0 = 1.0f / (1.0f + e10);
    tok_e[2 * n] = i0; tok_e[2 * n + 1] = i1;
    tok_w[2 * n] = w0; tok_w[2 * n + 1] = e10 / (1.0f + e10);
    atomicAdd(&counts[i0], 1); atomicAdd(&counts[i1], 1);
  }
}

__global__ void prefix_kernel(const int* __restrict__ counts, int* __restrict__ bases,
                              int* __restrict__ cursor) {
  if (threadIdx.x == 0) {
    int s = 0;
    for (int e = 0; e < EE; ++e) { bases[e] = s; s += counts[e]; }
    bases[EE] = s;
  }
  if (threadIdx.x < EE) cursor[threadIdx.x] = 0;
}

__global__ __launch_bounds__(256) void scatter_kernel(
    const int* __restrict__ tok_e, const float* __restrict__ tok_w,
    const int* __restrict__ bases, int* __restrict__ cursor,
    int* __restrict__ assign_token, float* __restrict__ assign_w) {
  int n = blockIdx.x * 256 + threadIdx.x;
  if (n >= NT) return;
#pragma unroll
  for (int k2 = 0; k2 < 2; ++k2) {
    int e = tok_e[2 * n + k2];
    int pos = atomicAdd(&cursor[e], 1);
    int slot = bases[e] + pos;
    assign_token[slot] = n;
    assign_w[slot] = tok_w[2 * n + k2];
  }
}

// ---------------- bcomb[e][d] = bu[e][d] + sum_f bg[e][f] * Wu^T[e][d][f] ----------------
__global__ __launch_bounds__(256) void bcomb_kernel(
    const ushort* __restrict__ wut, const float* __restrict__ bg,
    const float* __restrict__ bu, float* __restrict__ bc) {
  int gid = blockIdx.x * 4 + (threadIdx.x >> 6);
  int l = threadIdx.x & 63;
  int e = gid / DFFP, d = gid - e * DFFP;
  const ushort* row = wut + ((size_t)e * DFFP + d) * HH;
  const float* bge = bg + (size_t)e * HH;
  float s = 0.f;
#pragma unroll
  for (int i = 0; i < 4; ++i) {
    int k = (l + i * 64) * 4;
    ushort4 w4 = *(const ushort4*)&row[k];
    float4 b4 = *(const float4*)&bge[k];
    s += __uint_as_float((unsigned)w4.x << 16) * b4.x
       + __uint_as_float((unsigned)w4.y << 16) * b4.y
       + __uint_as_float((unsigned)w4.z << 16) * b4.z
       + __uint_as_float((unsigned)w4.w << 16) * b4.w;
  }
#pragma unroll
  for (int sh = 1; sh < 64; sh <<= 1) s += __shfl_xor(s, sh);
  if (l == 0) bc[(size_t)e * DFFP + d] = s + ((d < DFF) ? bu[(size_t)e * DFF + d] : 0.f);
}

// ---- grouped GEMM, 128x256 tile, BK=32, DOUBLE-buffer 48 KB -> 3 blocks/CU (R13 loop) ----
// Per K-step: STAGE(t+1) -> [LDS reads + MFMA, setprio] -> vmcnt(0) -> raw s_barrier.
// Per wave/tile: 6 gload16 (2 A + 4 B).  Arithmetic intensity 85 FLOP/staged-byte.
// All 4 waves share A rows (af[8]); wave w owns cols [w*64, w*64+64) of BN=256 (bfr[4]).
// MODE 3: dense  C[d][h] = sum_f wut[e][d][f] * wgn[e][h][f]  -> Wcombo^T (bf16, no bias)
// MODE 4: gather C = x[tok] @ Wcombo^T + bc, silu -> u (bf16, cols >= DFF zeroed)
// MODE 2:        C = u @ Wd^T + bd, y[tok] += w*C (atomic fp32)
template <int MODE, int MB, int NBT>
__global__ __launch_bounds__(256, 3) void moe_gemm_kernel(
    const ushort* __restrict__ Abase, const ushort* __restrict__ Wbase,
    const float* __restrict__ bias, ushort* __restrict__ outb, float* __restrict__ y,
    const int* __restrict__ bases, const int* __restrict__ assign_token,
    const float* __restrict__ assign_w,
    int K, int lda, long wstride_e, int bias_stride, int ldc,
    int ncols_valid, int ncols_write, int wrows) {
  constexpr int nwg = MB * NBT * EE;
  constexpr int q = nwg >> 3, r8 = nwg & 7;
  int orig = blockIdx.x;
  int xcd = orig & 7, pos = orig >> 3;
  int id = (xcd < r8 ? xcd * (q + 1) : r8 * (q + 1) + (xcd - r8) * q) + pos;
  int m = id % MB; int t2 = id / MB;
  int n = t2 % NBT;
  int e = t2 / NBT;

  int base, Ce;
  if (MODE == 3) { base = e * DFFP; Ce = DFFP; }
  else           { base = bases[e]; Ce = bases[e + 1] - base; }
  int m0 = m * 128;
  if (m0 >= Ce) return;
  int n0 = n * 256;
  int rows_valid = Ce - m0; if (rows_valid > 128) rows_valid = 128;

  // double buffer: buf b at b*12288 ushorts; A [128][32] at +0, B [256][32] at +4096.
  // 2 x 24 KB = 48 KB total -> 3 blocks/CU.
  __shared__ ushort lds[24576];
  int tid = threadIdx.x, w = tid >> 6, l = tid & 63;

  // staging: A 512 chunks (2/thread), B 1024 chunks (4/thread); dest linear,
  // src chunk pre-swizzled: csrc = (l&3) ^ ((l>>3)&3)
  const ushort* aptr[2];
  const ushort* bptr[4];
  int lofsA[2], lofsB[4];
  const ushort* We = Wbase + (size_t)e * wstride_e;
  int csrc = ((l & 3) ^ ((l >> 3) & 3)) * 8;
#pragma unroll
  for (int i = 0; i < 2; ++i) {
    int r = i * 64 + w * 16 + (l >> 2);
    int ar = r < rows_valid ? r : rows_valid - 1;
    int slot = base + m0 + ar;
    long arow = (MODE == 4) ? (long)assign_token[slot] : (long)slot;
    aptr[i] = Abase + arow * (long)lda + csrc;
    lofsA[i] = (i * 256 + w * 64) * 8;
  }
#pragma unroll
  for (int i = 0; i < 4; ++i) {
    int r = i * 64 + w * 16 + (l >> 2);
    int wr = n0 + r; if (wr >= wrows) wr = wrows - 1;
    bptr[i] = We + (size_t)wr * K + csrc;
    lofsB[i] = 4096 + (i * 256 + w * 64) * 8;
  }

  f32x4 acc[8][4];
#pragma unroll
  for (int a1 = 0; a1 < 8; ++a1)
#pragma unroll
    for (int b1 = 0; b1 < 4; ++b1) acc[a1][b1] = f32x4{0.f, 0.f, 0.f, 0.f};

  int nk = K >> 5;
  // prologue: stage tile 0 -> buf 0, full drain
#pragma unroll
  for (int i = 0; i < 2; ++i) gload16(aptr[i], &lds[lofsA[i]]);
#pragma unroll
  for (int i = 0; i < 4; ++i) gload16(bptr[i], &lds[lofsB[i]]);
  asm volatile("s_waitcnt vmcnt(0)" ::: "memory");
  __builtin_amdgcn_s_barrier();

  int l15 = l & 15, lhi = l >> 4;
  int cirx = (lhi ^ ((l15 >> 1) & 3)) * 8;
  int cur = 0;
  for (int t = 0; t < nk; ++t) {
    int nxt = cur ^ 1;
    if (t + 1 < nk) {
      int k0 = (t + 1) << 5;
      int sb = nxt * 12288;
#pragma unroll
      for (int i = 0; i < 2; ++i) gload16(aptr[i] + k0, &lds[sb + lofsA[i]]);
#pragma unroll
      for (int i = 0; i < 4; ++i) gload16(bptr[i] + k0, &lds[sb + lofsB[i]]);
    }
    const ushort* cA = &lds[cur * 12288];
    const ushort* cB = &lds[cur * 12288 + 4096];
    bf16x8 af[8], bfr[4];
#pragma unroll
    for (int mt = 0; mt < 8; ++mt) {
      int row = mt * 16 + l15;
      af[mt] = *(const bf16x8*)&cA[row * 32 + cirx];
    }
#pragma unroll
    for (int nt = 0; nt < 4; ++nt) {
      int row = w * 64 + nt * 16 + l15;
      bfr[nt] = *(const bf16x8*)&cB[row * 32 + cirx];
    }
    __builtin_amdgcn_s_setprio(1);
#pragma unroll
    for (int mt = 0; mt < 8; ++mt)
#pragma unroll
      for (int nt = 0; nt < 4; ++nt)
        acc[mt][nt] = __builtin_amdgcn_mfma_f32_16x16x32_bf16(af[mt], bfr[nt], acc[mt][nt], 0, 0, 0);
    __builtin_amdgcn_s_setprio(0);
    asm volatile("s_waitcnt vmcnt(0)" ::: "memory");  // t+1 staged (hidden under MFMA)
    __builtin_amdgcn_s_barrier();
    cur = nxt;
  }

  int lr = l >> 4, lc = l & 15;
#pragma unroll
  for (int mt = 0; mt < 8; ++mt) {
#pragma unroll
    for (int i2 = 0; i2 < 4; ++i2) {
      int r = mt * 16 + lr * 4 + i2;
      if (r >= rows_valid) continue;
      int slot = base + m0 + r;
      int tok = 0; float wgt = 0.f;
      if (MODE == 2) { tok = assign_token[slot]; wgt = assign_w[slot]; }
#pragma unroll
      for (int nt = 0; nt < 4; ++nt) {
        int col = n0 + w * 64 + nt * 16 + lc;
        if (col >= ncols_write) continue;
        float v = acc[mt][nt][i2];
        if (MODE == 3) {
          outb[(size_t)slot * ldc + col] = f2bf(v);
        } else if (MODE == 4) {
          float o = 0.0f;
          if (col < ncols_valid) {
            v += bias[(size_t)e * bias_stride + col];
            o = v / (1.0f + __expf(-v));
          }
          outb[(size_t)slot * ldc + col] = f2bf(o);
        } else {
          v += bias[(size_t)e * bias_stride + col];
          atomicAdd(&y[(size_t)tok * HH + col], wgt * v);
        }
      }
    }
  }
}

extern "C" void kernel_launch(void* const* d_in, const int* in_sizes, int n_in,
                              void* d_out, int out_size, void* d_ws, size_t ws_size,
                              hipStream_t stream) {
  const float* x  = (const float*)d_in[0];
  const float* Wr = (const float*)d_in[1];
  const float* br = (const float*)d_in[2];
  const float* Wg = (const float*)d_in[3];
  const float* bg = (const float*)d_in[4];
  const float* Wu = (const float*)d_in[5];
  const float* bu = (const float*)d_in[6];
  const float* Wd = (const float*)d_in[7];
  const float* bd = (const float*)d_in[8];
  float* y = (float*)d_out;
  float* logits = y + YSZ;

  // workspace layout (bytes)
  char* ws = (char*)d_ws;
  size_t o = 0;
  auto alloc = [&](size_t b) { size_t r = o; o = (o + b + 255) & ~(size_t)255; return r; };
  size_t XB  = alloc((size_t)NT * HH * 2);            // x bf16
  size_t WGN = alloc((size_t)EE * HH * HH * 2);       // Wg bf16 (ORIGINAL [h][f] layout)
  size_t WUT = alloc((size_t)EE * DFFP * HH * 2);     // Wu^T bf16
  size_t WDT = alloc((size_t)EE * HH * DFFP * 2);     // Wd^T bf16
  size_t WCB = alloc((size_t)EE * DFFP * HH * 2);     // Wcombo^T bf16
  size_t U   = alloc((size_t)NA * DFFP * 2);          // u bf16
  size_t BC  = alloc((size_t)EE * DFFP * 4);          // bcomb fp32
  size_t META = alloc(262400);

  ushort* xb  = (ushort*)(ws + XB);
  ushort* wgn = (ushort*)(ws + WGN);
  ushort* wut = (ushort*)(ws + WUT);
  ushort* wdt = (ushort*)(ws + WDT);
  ushort* wcb = (ushort*)(ws + WCB);
  ushort* u   = (ushort*)(ws + U);
  float* bcomb = (float*)(ws + BC);
  int* meta = (int*)(ws + META);
  int* counts = meta;                 // 8
  int* bases  = meta + 16;            // 9
  int* cursor = meta + 32;            // 8
  int* tok_e  = meta + 64;            // 16384
  float* tok_w = (float*)(tok_e + NA);
  int* assign_token = (int*)(tok_w + NA);
  float* assign_w = (float*)(assign_token + NA);

  hipMemsetAsync(y, 0, YSZ * sizeof(float), stream);
  hipMemsetAsync(meta, 0, 256, stream);

  // routing (fused x->bf16), weight converts/transposes, scatter, combined bias
  router_kernel<<<NT / 4, 256, 0, stream>>>(x, Wr, br, logits, counts, tok_e, tok_w, xb);
  cvt_w_kernel<<<(EE * HH * HH / 4 + 255) / 256, 256, 0, stream>>>(
      (const float4*)Wg, (ushort4*)wgn, EE * HH * HH / 4);
  transpose_cvt_kernel<<<dim3(DFFP / 64, 16, EE), 256, 0, stream>>>(Wu, wut, HH, DFF, HH, DFFP,
                                                                    (long)HH * DFF, (long)DFFP * HH);
  transpose_cvt_kernel<<<dim3(16, DFFP / 64, EE), 256, 0, stream>>>(Wd, wdt, DFF, HH, DFFP, HH,
                                                                    (long)DFF * HH, (long)HH * DFFP);
  prefix_kernel<<<1, 64, 0, stream>>>(counts, bases, cursor);
  scatter_kernel<<<NT / 256, 256, 0, stream>>>(tok_e, tok_w, bases, cursor, assign_token, assign_w);
  bcomb_kernel<<<EE * DFFP / 4, 256, 0, stream>>>(wut, bg, bu, bcomb);

  // Wcombo^T[e][d][h] = sum_f Wu^T[e][d][f] * Wg[e][h][f]  -- dense; MB=22, NBT=4
  moe_gemm_kernel<3, 22, 4><<<22 * 4 * EE, 256, 0, stream>>>(
      wut, wgn, nullptr, wcb, nullptr, nullptr, nullptr, nullptr,
      HH, HH, (long)HH * HH, 0, HH, HH, HH, HH);
  // u = silu(gather(xb) @ Wcombo^T + bcomb)  -- MB=17, NBT=11 (2816 cols, clamped to 2752)
  moe_gemm_kernel<4, 17, 11><<<17 * 11 * EE, 256, 0, stream>>>(
      xb, wcb, bcomb, u, nullptr, bases, assign_token, nullptr,
      HH, HH, (long)DFFP * HH, DFFP, DFFP, DFF, DFFP, DFFP);
  // y[tok] += w * (u @ Wd^T + bd)  -- MB=17, NBT=4
  moe_gemm_kernel<2, 17, 4><<<17 * 4 * EE, 256, 0, stream>>>(
      u, wdt, bd, nullptr, y, bases, assign_token, assign_w,
      DFFP, DFFP, (long)HH * DFFP, HH, HH, HH, HH, HH);
}

// Round 19
// 784.975 us; speedup vs baseline: 2.0260x; 2.0260x over previous
//
#include <hip/hip_runtime.h>
#include <hip/hip_bf16.h>

// Problem constants
#define NB 4
#define SS 2048
#define HH 1024
#define EE 8
#define KK 2
#define DFF 2730
#define DFFP 2752           // padded to multiple of 64
#define NT (NB*SS)          // 8192 tokens
#define NA (NT*KK)          // 16384 assignments
#define YSZ ((size_t)NT*HH) // 8388608

using bf16x8 = __attribute__((ext_vector_type(8))) short;
using f32x4  = __attribute__((ext_vector_type(4))) float;

__device__ __forceinline__ ushort f2bf(float f) {
  unsigned u = __float_as_uint(f);
  unsigned r = (u + 0x7FFFu + ((u >> 16) & 1u)) >> 16;
  return (ushort)r;
}

__device__ __forceinline__ void gload16(const ushort* g, ushort* s) {
  __builtin_amdgcn_global_load_lds((const __attribute__((address_space(1))) void*)g,
                                   (__attribute__((address_space(3))) void*)s, 16, 0, 0);
}

// ---------------- plain fp32 -> bf16 convert (no transpose) ----------------
__global__ __launch_bounds__(256) void cvt_w_kernel(const float4* __restrict__ in4,
                                                    ushort4* __restrict__ o4, int n4) {
  int i = blockIdx.x * 256 + threadIdx.x;
  if (i >= n4) return;
  float4 v = in4[i];
  ushort4 o;
  o.x = f2bf(v.x); o.y = f2bf(v.y); o.z = f2bf(v.z); o.w = f2bf(v.w);
  o4[i] = o;
}

// ------------- transpose + convert: in[e][K][Nn] fp32 -> out[e][Nnpad][Kpad] bf16 -------------
__global__ __launch_bounds__(256) void transpose_cvt_kernel(
    const float* __restrict__ in, ushort* __restrict__ out,
    int K, int Nn, int Kpad, int Nnpad, long in_estride, long out_estride) {
  __shared__ float t[64][65];   // t[k_local][n_local]
  int e = blockIdx.z;
  const float* ine = in + (size_t)e * in_estride;
  ushort* oute = out + (size_t)e * out_estride;
  int nb = blockIdx.x * 64, kb = blockIdx.y * 64;
  int tid = threadIdx.x;
  int rr = tid >> 4, cc = (tid & 15) * 4;
  if (kb + 64 <= K && nb + 64 <= Nn) {
#pragma unroll
    for (int i = 0; i < 4; ++i) {
      int r = rr + i * 16;
      const float* src = ine + (size_t)(kb + r) * Nn + nb + cc;
      float2 a = *(const float2*)src;
      float2 b = *(const float2*)(src + 2);
      t[r][cc] = a.x; t[r][cc + 1] = a.y; t[r][cc + 2] = b.x; t[r][cc + 3] = b.y;
    }
  } else {
#pragma unroll
    for (int i = 0; i < 4; ++i) {
      int r = rr + i * 16;
      int kg = kb + r;
#pragma unroll
      for (int j = 0; j < 4; ++j) {
        int ng = nb + cc + j;
        t[r][cc + j] = (kg < K && ng < Nn) ? ine[(size_t)kg * Nn + ng] : 0.0f;
      }
    }
  }
  __syncthreads();
  int kq = tid & 15;
#pragma unroll
  for (int i = 0; i < 4; ++i) {
    int nl = rr + i * 16, ng = nb + nl;
    ushort4 v;
    v.x = f2bf(t[kq * 4 + 0][nl]);
    v.y = f2bf(t[kq * 4 + 1][nl]);
    v.z = f2bf(t[kq * 4 + 2][nl]);
    v.w = f2bf(t[kq * 4 + 3][nl]);
    *(ushort4*)&oute[(size_t)ng * Kpad + kb + kq * 4] = v;
  }
}

// ---------------- router (+ fused x->bf16 convert): logits, top2, counts ----------------
__global__ __launch_bounds__(256) void router_kernel(
    const float* __restrict__ x, const float* __restrict__ Wr, const float* __restrict__ br,
    float* __restrict__ logits_out, int* __restrict__ counts,
    int* __restrict__ tok_e, float* __restrict__ tok_w, ushort* __restrict__ xb) {
  int wv = threadIdx.x >> 6, l = threadIdx.x & 63;
  int n = blockIdx.x * 4 + wv;
  const float* xr = x + (size_t)n * HH;
  ushort* xbr = xb + (size_t)n * HH;
  float acc[8] = {0, 0, 0, 0, 0, 0, 0, 0};
#pragma unroll 4
  for (int i = 0; i < 16; ++i) {
    int k = l + i * 64;
    float xv = xr[k];
    xbr[k] = f2bf(xv);              // fused convert (x is read here anyway)
    const float4* w4 = (const float4*)(Wr + (size_t)k * 8);
    float4 a = w4[0], b = w4[1];
    acc[0] += xv * a.x; acc[1] += xv * a.y; acc[2] += xv * a.z; acc[3] += xv * a.w;
    acc[4] += xv * b.x; acc[5] += xv * b.y; acc[6] += xv * b.z; acc[7] += xv * b.w;
  }
#pragma unroll
  for (int s = 1; s < 64; s <<= 1)
#pragma unroll
    for (int e2 = 0; e2 < 8; ++e2) acc[e2] += __shfl_xor(acc[e2], s);
#pragma unroll
  for (int e2 = 0; e2 < 8; ++e2) acc[e2] += br[e2];
  if (l < 8) logits_out[(size_t)n * 8 + l] = acc[l];
  if (l == 0) {
    int i0 = 0;
#pragma unroll
    for (int e2 = 1; e2 < 8; ++e2) if (acc[e2] > acc[i0]) i0 = e2;
    int i1 = (i0 == 0) ? 1 : 0;
#pragma unroll
    for (int e2 = 0; e2 < 8; ++e2) if (e2 != i0 && acc[e2] > acc[i1]) i1 = e2;
    float e10 = __expf(acc[i1] - acc[i0]);
    float w0 = 1.0f / (1.0f + e10);
    tok_e[2 * n] = i0; tok_e[2 * n + 1] = i1;
    tok_w[2 * n] = w0; tok_w[2 * n + 1] = e10 / (1.0f + e10);
    atomicAdd(&counts[i0], 1); atomicAdd(&counts[i1], 1);
  }
}

__global__ void prefix_kernel(const int* __restrict__ counts, int* __restrict__ bases,
                              int* __restrict__ cursor) {
  if (threadIdx.x == 0) {
    int s = 0;
    for (int e = 0; e < EE; ++e) { bases[e] = s; s += counts[e]; }
    bases[EE] = s;
  }
  if (threadIdx.x < EE) cursor[threadIdx.x] = 0;
}

__global__ __launch_bounds__(256) void scatter_kernel(
    const int* __restrict__ tok_e, const float* __restrict__ tok_w,
    const int* __restrict__ bases, int* __restrict__ cursor,
    int* __restrict__ assign_token, float* __restrict__ assign_w) {
  int n = blockIdx.x * 256 + threadIdx.x;
  if (n >= NT) return;
#pragma unroll
  for (int k2 = 0; k2 < 2; ++k2) {
    int e = tok_e[2 * n + k2];
    int pos = atomicAdd(&cursor[e], 1);
    int slot = bases[e] + pos;
    assign_token[slot] = n;
    assign_w[slot] = tok_w[2 * n + k2];
  }
}

// ---------------- bcomb[e][d] = bu[e][d] + sum_f bg[e][f] * Wu^T[e][d][f] ----------------
__global__ __launch_bounds__(256) void bcomb_kernel(
    const ushort* __restrict__ wut, const float* __restrict__ bg,
    const float* __restrict__ bu, float* __restrict__ bc) {
  int gid = blockIdx.x * 4 + (threadIdx.x >> 6);
  int l = threadIdx.x & 63;
  int e = gid / DFFP, d = gid - e * DFFP;
  const ushort* row = wut + ((size_t)e * DFFP + d) * HH;
  const float* bge = bg + (size_t)e * HH;
  float s = 0.f;
#pragma unroll
  for (int i = 0; i < 4; ++i) {
    int k = (l + i * 64) * 4;
    ushort4 w4 = *(const ushort4*)&row[k];
    float4 b4 = *(const float4*)&bge[k];
    s += __uint_as_float((unsigned)w4.x << 16) * b4.x
       + __uint_as_float((unsigned)w4.y << 16) * b4.y
       + __uint_as_float((unsigned)w4.z << 16) * b4.z
       + __uint_as_float((unsigned)w4.w << 16) * b4.w;
  }
#pragma unroll
  for (int sh = 1; sh < 64; sh <<= 1) s += __shfl_xor(s, sh);
  if (l == 0) bc[(size_t)e * DFFP + d] = s + ((d < DFF) ? bu[(size_t)e * DFF + d] : 0.f);
}

// ---------------- grouped GEMM, 128x128 tile, BK=32, dbuf 32KB -> 4 blocks/CU ------------
// (R13 best-measured config.) Loop: STAGE(t+1) -> [LDS reads + MFMA, setprio] -> vmcnt(0)
// -> raw s_barrier.  Swizzle (4 chunks/row): dest c holds src c^((r>>1)&3); reader inverts.
// MODE 3: dense  C[d][h] = sum_f wut[e][d][f] * wgn[e][h][f]  -> Wcombo^T (bf16, no bias)
// MODE 4: gather C = x[tok] @ Wcombo^T + bc, silu -> u (bf16, cols >= DFF zeroed)
// MODE 2:        C = u @ Wd^T + bd, y[tok] += w*C (atomic fp32)
template <int MODE, int MB, int NBT>
__global__ __launch_bounds__(256, 4) void moe_gemm_kernel(
    const ushort* __restrict__ Abase, const ushort* __restrict__ Wbase,
    const float* __restrict__ bias, ushort* __restrict__ outb, float* __restrict__ y,
    const int* __restrict__ bases, const int* __restrict__ assign_token,
    const float* __restrict__ assign_w,
    int K, int lda, long wstride_e, int bias_stride, int ldc,
    int ncols_valid, int ncols_write, int wrows) {
  constexpr int nwg = MB * NBT * EE;
  constexpr int q = nwg >> 3, r8 = nwg & 7;
  int orig = blockIdx.x;
  int xcd = orig & 7, pos = orig >> 3;
  int id = (xcd < r8 ? xcd * (q + 1) : r8 * (q + 1) + (xcd - r8) * q) + pos;
  int m = id % MB; int t2 = id / MB;
  int n = t2 % NBT;
  int e = t2 / NBT;

  int base, Ce;
  if (MODE == 3) { base = e * DFFP; Ce = DFFP; }
  else           { base = bases[e]; Ce = bases[e + 1] - base; }
  int m0 = m * 128;
  if (m0 >= Ce) return;
  int n0 = n * 128;
  int rows_valid = Ce - m0; if (rows_valid > 128) rows_valid = 128;

  // dbuf: buf b -> A at b*8192, B at b*8192+4096 (ushort idx). 32 KiB total.
  __shared__ ushort lds[16384];
  int tid = threadIdx.x, w = tid >> 6, l = tid & 63;
  int wm = w >> 1, wn = w & 1;

  // staging: 512 chunks (16B) per matrix, 2 per thread; dest linear, src pre-swizzled
  const ushort* aptr[2];
  const ushort* bptr[2];
  int lofs[2];
  const ushort* We = Wbase + (size_t)e * wstride_e;
  int csrc = ((l & 3) ^ ((l >> 3) & 3)) * 8;
#pragma unroll
  for (int i = 0; i < 2; ++i) {
    int r = i * 64 + w * 16 + (l >> 2);
    int ar = r < rows_valid ? r : rows_valid - 1;
    int slot = base + m0 + ar;
    long arow = (MODE == 4) ? (long)assign_token[slot] : (long)slot;
    aptr[i] = Abase + arow * (long)lda + csrc;
    int wr = n0 + r; if (wr >= wrows) wr = wrows - 1;
    bptr[i] = We + (size_t)wr * K + csrc;
    lofs[i] = (i * 256 + w * 64) * 8;
  }

  f32x4 acc[4][4];
#pragma unroll
  for (int a1 = 0; a1 < 4; ++a1)
#pragma unroll
    for (int b1 = 0; b1 < 4; ++b1) acc[a1][b1] = f32x4{0.f, 0.f, 0.f, 0.f};

  int nk = K >> 5;
#pragma unroll
  for (int i = 0; i < 2; ++i) {
    gload16(aptr[i], &lds[lofs[i]]);
    gload16(bptr[i], &lds[4096 + lofs[i]]);
  }
  asm volatile("s_waitcnt vmcnt(0)" ::: "memory");
  __builtin_amdgcn_s_barrier();

  int l15 = l & 15, lhi = l >> 4;
  int cur = 0;
  for (int t = 0; t < nk; ++t) {
    int nxt = cur ^ 1;
    if (t + 1 < nk) {
      int k0 = (t + 1) << 5;
#pragma unroll
      for (int i = 0; i < 2; ++i) {
        gload16(aptr[i] + k0, &lds[nxt * 8192 + lofs[i]]);
        gload16(bptr[i] + k0, &lds[nxt * 8192 + 4096 + lofs[i]]);
      }
    }
    const ushort* cA = &lds[cur * 8192];
    const ushort* cB = &lds[cur * 8192 + 4096];
    bf16x8 af[4], bfr[4];
#pragma unroll
    for (int mt = 0; mt < 4; ++mt) {
      int row = wm * 64 + mt * 16 + l15;
      int cir = lhi ^ ((l15 >> 1) & 3);
      af[mt] = *(const bf16x8*)&cA[row * 32 + cir * 8];
    }
#pragma unroll
    for (int nt = 0; nt < 4; ++nt) {
      int row = wn * 64 + nt * 16 + l15;
      int cir = lhi ^ ((l15 >> 1) & 3);
      bfr[nt] = *(const bf16x8*)&cB[row * 32 + cir * 8];
    }
    __builtin_amdgcn_s_setprio(1);
#pragma unroll
    for (int mt = 0; mt < 4; ++mt)
#pragma unroll
      for (int nt = 0; nt < 4; ++nt)
        acc[mt][nt] = __builtin_amdgcn_mfma_f32_16x16x32_bf16(af[mt], bfr[nt], acc[mt][nt], 0, 0, 0);
    __builtin_amdgcn_s_setprio(0);
    asm volatile("s_waitcnt vmcnt(0)" ::: "memory");  // t+1 staged (hidden under MFMA)
    __builtin_amdgcn_s_barrier();
    cur = nxt;
  }

  int lr = l >> 4, lc = l & 15;
#pragma unroll
  for (int mt = 0; mt < 4; ++mt) {
#pragma unroll
    for (int i2 = 0; i2 < 4; ++i2) {
      int r = wm * 64 + mt * 16 + lr * 4 + i2;
      if (r >= rows_valid) continue;
      int slot = base + m0 + r;
      int tok = 0; float wgt = 0.f;
      if (MODE == 2) { tok = assign_token[slot]; wgt = assign_w[slot]; }
#pragma unroll
      for (int nt = 0; nt < 4; ++nt) {
        int col = n0 + wn * 64 + nt * 16 + lc;
        if (col >= ncols_write) continue;
        float v = acc[mt][nt][i2];
        if (MODE == 3) {
          outb[(size_t)slot * ldc + col] = f2bf(v);
        } else if (MODE == 4) {
          float o = 0.0f;
          if (col < ncols_valid) {
            v += bias[(size_t)e * bias_stride + col];
            o = v / (1.0f + __expf(-v));
          }
          outb[(size_t)slot * ldc + col] = f2bf(o);
        } else {
          v += bias[(size_t)e * bias_stride + col];
          atomicAdd(&y[(size_t)tok * HH + col], wgt * v);
        }
      }
    }
  }
}

extern "C" void kernel_launch(void* const* d_in, const int* in_sizes, int n_in,
                              void* d_out, int out_size, void* d_ws, size_t ws_size,
                              hipStream_t stream) {
  const float* x  = (const float*)d_in[0];
  const float* Wr = (const float*)d_in[1];
  const float* br = (const float*)d_in[2];
  const float* Wg = (const float*)d_in[3];
  const float* bg = (const float*)d_in[4];
  const float* Wu = (const float*)d_in[5];
  const float* bu = (const float*)d_in[6];
  const float* Wd = (const float*)d_in[7];
  const float* bd = (const float*)d_in[8];
  float* y = (float*)d_out;
  float* logits = y + YSZ;

  // workspace layout (bytes)
  char* ws = (char*)d_ws;
  size_t o = 0;
  auto alloc = [&](size_t b) { size_t r = o; o = (o + b + 255) & ~(size_t)255; return r; };
  size_t XB  = alloc((size_t)NT * HH * 2);            // x bf16
  size_t WGN = alloc((size_t)EE * HH * HH * 2);       // Wg bf16 (ORIGINAL [h][f] layout)
  size_t WUT = alloc((size_t)EE * DFFP * HH * 2);     // Wu^T bf16
  size_t WDT = alloc((size_t)EE * HH * DFFP * 2);     // Wd^T bf16
  size_t WCB = alloc((size_t)EE * DFFP * HH * 2);     // Wcombo^T bf16
  size_t U   = alloc((size_t)NA * DFFP * 2);          // u bf16
  size_t BC  = alloc((size_t)EE * DFFP * 4);          // bcomb fp32
  size_t META = alloc(262400);

  ushort* xb  = (ushort*)(ws + XB);
  ushort* wgn = (ushort*)(ws + WGN);
  ushort* wut = (ushort*)(ws + WUT);
  ushort* wdt = (ushort*)(ws + WDT);
  ushort* wcb = (ushort*)(ws + WCB);
  ushort* u   = (ushort*)(ws + U);
  float* bcomb = (float*)(ws + BC);
  int* meta = (int*)(ws + META);
  int* counts = meta;                 // 8
  int* bases  = meta + 16;            // 9
  int* cursor = meta + 32;            // 8
  int* tok_e  = meta + 64;            // 16384
  float* tok_w = (float*)(tok_e + NA);
  int* assign_token = (int*)(tok_w + NA);
  float* assign_w = (float*)(assign_token + NA);

  hipMemsetAsync(y, 0, YSZ * sizeof(float), stream);
  hipMemsetAsync(meta, 0, 256, stream);

  // routing (fused x->bf16), weight converts/transposes, scatter, combined bias
  router_kernel<<<NT / 4, 256, 0, stream>>>(x, Wr, br, logits, counts, tok_e, tok_w, xb);
  cvt_w_kernel<<<(EE * HH * HH / 4 + 255) / 256, 256, 0, stream>>>(
      (const float4*)Wg, (ushort4*)wgn, EE * HH * HH / 4);
  transpose_cvt_kernel<<<dim3(DFFP / 64, 16, EE), 256, 0, stream>>>(Wu, wut, HH, DFF, HH, DFFP,
                                                                    (long)HH * DFF, (long)DFFP * HH);
  transpose_cvt_kernel<<<dim3(16, DFFP / 64, EE), 256, 0, stream>>>(Wd, wdt, DFF, HH, DFFP, HH,
                                                                    (long)DFF * HH, (long)HH * DFFP);
  prefix_kernel<<<1, 64, 0, stream>>>(counts, bases, cursor);
  scatter_kernel<<<NT / 256, 256, 0, stream>>>(tok_e, tok_w, bases, cursor, assign_token, assign_w);
  bcomb_kernel<<<EE * DFFP / 4, 256, 0, stream>>>(wut, bg, bu, bcomb);

  // Wcombo^T[e][d][h] = sum_f Wu^T[e][d][f] * Wg[e][h][f]  -- dense, 128x128 tiles
  moe_gemm_kernel<3, 22, 8><<<22 * 8 * EE, 256, 0, stream>>>(
      wut, wgn, nullptr, wcb, nullptr, nullptr, nullptr, nullptr,
      HH, HH, (long)HH * HH, 0, HH, HH, HH, HH);
  // u = silu(gather(xb) @ Wcombo^T + bcomb)
  moe_gemm_kernel<4, 17, 22><<<17 * 22 * EE, 256, 0, stream>>>(
      xb, wcb, bcomb, u, nullptr, bases, assign_token, nullptr,
      HH, HH, (long)DFFP * HH, DFFP, DFFP, DFF, DFFP, DFFP);
  // y[tok] += w * (u @ Wd^T + bd)
  moe_gemm_kernel<2, 17, 8><<<17 * 8 * EE, 256, 0, stream>>>(
      u, wdt, bd, nullptr, y, bases, assign_token, assign_w,
      DFFP, DFFP, (long)HH * DFFP, HH, HH, HH, HH, HH);
}